// Round 14
// baseline (6422.681 us; speedup 1.0000x reference)
//
#include <hip/hip_runtime.h>

// ---------- types ----------
typedef float  f32x4  __attribute__((ext_vector_type(4)));
typedef unsigned short u16x4 __attribute__((ext_vector_type(4)));
typedef unsigned short u16x8 __attribute__((ext_vector_type(8)));
typedef __bf16 bf16x8 __attribute__((ext_vector_type(8)));

// round-to-nearest-even f32 -> bf16 (bit trick)
static __device__ __forceinline__ unsigned short bf16_rn(float x) {
  unsigned u = __builtin_bit_cast(unsigned, x);
  unsigned r = (u + 0x7FFFu + ((u >> 16) & 1u)) >> 16;
  return (unsigned short)r;
}
// split x ~= hi + lo (each bf16); residual ~2^-17 relative
static __device__ __forceinline__ void split1(float x, unsigned short& h, unsigned short& l) {
  unsigned short hh = bf16_rn(x);
  float hf = __builtin_bit_cast(float, ((unsigned)hh) << 16);
  h = hh;
  l = bf16_rn(x - hf);
}

#define BM 128
#define BN 128
#define BK 32

// LDS tile [128 rows][32 u16], 64B rows, XOR chunk swizzle.
static __device__ __forceinline__ int lds_i32(int row, int k) {
  return (row << 5) + ((((k >> 3) ^ (row >> 2)) & 3) << 3) + (k & 7);
}

// async global->LDS, 16B per lane
static __device__ __forceinline__ void gld16(const unsigned short* g, unsigned short* l) {
  __builtin_amdgcn_global_load_lds(
      (const __attribute__((address_space(1))) void*)g,
      (__attribute__((address_space(3))) void*)l, 16, 0, 0);
}

// ---------- GEMM (pre-split inputs): C = A * B^T + bias ----------
__global__ __launch_bounds__(256) void gemm_ps(
    const unsigned short* __restrict__ Ahg, const unsigned short* __restrict__ Alg,
    const unsigned short* __restrict__ Bhg, const unsigned short* __restrict__ Blg,
    const float* __restrict__ bias, float* __restrict__ C,
    int M, int N, int K) {
  __shared__ unsigned short Ah[BM * 32];
  __shared__ unsigned short Al[BM * 32];
  __shared__ unsigned short Bh[BN * 32];
  __shared__ unsigned short Bl[BN * 32];

  const int tid  = threadIdx.x;
  const int lane = tid & 63;
  const int wave = tid >> 6;
  const int bm = blockIdx.x * BM;
  const int bn = blockIdx.y * BN;
  const int wm = (wave >> 1) * 64;
  const int wn = (wave & 1) * 64;

  f32x4 acc[4][4] = {};

  const int rl = lane >> 2;
  const int ch = lane & 3;

  for (int k0 = 0; k0 < K; k0 += BK) {
#pragma unroll
    for (int i = 0; i < 2; ++i) {
      int r0  = ((wave << 1) + i) << 4;
      int row = r0 + rl;
      int gc  = ch ^ ((row >> 2) & 3);
      size_t ga = (size_t)(bm + row) * K + k0 + (gc << 3);
      size_t gb = (size_t)(bn + row) * K + k0 + (gc << 3);
      int lb = r0 << 5;
      gld16(Ahg + ga, &Ah[lb]);
      gld16(Alg + ga, &Al[lb]);
      gld16(Bhg + gb, &Bh[lb]);
      gld16(Blg + gb, &Bl[lb]);
    }
    __syncthreads();

    const int fr = lane & 15;
    const int kg = (lane >> 4) << 3;
    u16x8 a_h[4], a_l[4], b_h[4], b_l[4];
#pragma unroll
    for (int i = 0; i < 4; ++i) {
      int ia = lds_i32(wm + i * 16 + fr, kg);
      int ib = lds_i32(wn + i * 16 + fr, kg);
      a_h[i] = *(const u16x8*)(&Ah[ia]);
      a_l[i] = *(const u16x8*)(&Al[ia]);
      b_h[i] = *(const u16x8*)(&Bh[ib]);
      b_l[i] = *(const u16x8*)(&Bl[ib]);
    }
#pragma unroll
    for (int i = 0; i < 4; ++i)
#pragma unroll
      for (int j = 0; j < 4; ++j) {
        acc[i][j] = __builtin_amdgcn_mfma_f32_16x16x32_bf16(
            __builtin_bit_cast(bf16x8, a_h[i]), __builtin_bit_cast(bf16x8, b_h[j]), acc[i][j], 0, 0, 0);
        acc[i][j] = __builtin_amdgcn_mfma_f32_16x16x32_bf16(
            __builtin_bit_cast(bf16x8, a_h[i]), __builtin_bit_cast(bf16x8, b_l[j]), acc[i][j], 0, 0, 0);
        acc[i][j] = __builtin_amdgcn_mfma_f32_16x16x32_bf16(
            __builtin_bit_cast(bf16x8, a_l[i]), __builtin_bit_cast(bf16x8, b_h[j]), acc[i][j], 0, 0, 0);
      }
    __syncthreads();
  }
  const int cc = lane & 15;
  const int rg = (lane >> 4) << 2;
#pragma unroll
  for (int i = 0; i < 4; ++i)
#pragma unroll
    for (int j = 0; j < 4; ++j)
#pragma unroll
      for (int r = 0; r < 4; ++r) {
        int row = bm + wm + i * 16 + rg + r;
        int col = bn + wn + j * 16 + cc;
        if (col < N) {
          float v = acc[i][j][r];
          if (bias) v += bias[col];
          C[(size_t)row * N + col] = v;
        }
      }
}

// ---------- legacy dense-flag poll (fallback path only) ----------
static __device__ __forceinline__ void poll_flags(const unsigned* flags, unsigned tgt, int lane) {
  for (;;) {
    unsigned v0 = __hip_atomic_load(flags + lane,       __ATOMIC_RELAXED, __HIP_MEMORY_SCOPE_AGENT);
    unsigned v1 = __hip_atomic_load(flags + 64 + lane,  __ATOMIC_RELAXED, __HIP_MEMORY_SCOPE_AGENT);
    unsigned v2 = __hip_atomic_load(flags + 128 + lane, __ATOMIC_RELAXED, __HIP_MEMORY_SCOPE_AGENT);
    unsigned v3 = __hip_atomic_load(flags + 192 + lane, __ATOMIC_RELAXED, __HIP_MEMORY_SCOPE_AGENT);
    unsigned m01 = v0 < v1 ? v0 : v1;
    unsigned m23 = v2 < v3 ? v2 : v3;
    unsigned mn  = m01 < m23 ? m01 : m23;
    if (__all((int)(mn >= tgt))) break;
    __builtin_amdgcn_s_sleep(1);
  }
  asm volatile("" ::: "memory");
}

// ---------- shared helpers ----------
static __device__ __forceinline__ void load_wset(
    const float* __restrict__ WT, int gcol, int wkoff,
    bf16x8* wh, bf16x8* wl) {
#pragma unroll
  for (int kk = 0; kk < 8; ++kk) {
    const float* src = WT + ((size_t)gcol << 10) + (wkoff + (kk << 5));
    f32x4 v0 = *(const f32x4*)src;
    f32x4 v1 = *(const f32x4*)(src + 4);
    u16x8 h8, l8;
#pragma unroll
    for (int j = 0; j < 4; ++j) {
      unsigned short hh, ll;
      split1(v0[j], hh, ll); h8[j] = hh;     l8[j] = ll;
      split1(v1[j], hh, ll); h8[4 + j] = hh; l8[4 + j] = ll;
    }
    wh[kk] = __builtin_bit_cast(bf16x8, h8);
    wl[kk] = __builtin_bit_cast(bf16x8, l8);
  }
}

static __device__ __forceinline__ void split_a(
    const float* __restrict__ hp, bf16x8& ah, bf16x8& al) {
  f32x4 v0 = *(const f32x4*)hp;
  f32x4 v1 = *(const f32x4*)(hp + 4);
  u16x8 h8, l8;
#pragma unroll
  for (int j = 0; j < 4; ++j) {
    unsigned short hh, ll;
    split1(v0[j], hh, ll); h8[j] = hh;     l8[j] = ll;
    split1(v1[j], hh, ll); h8[4 + j] = hh; l8[4 + j] = ll;
  }
  ah = __builtin_bit_cast(bf16x8, h8);
  al = __builtin_bit_cast(bf16x8, l8);
}

static __device__ __forceinline__ void dot3(
    const float* __restrict__ hsrc, int off,
    const bf16x8* wh, const bf16x8* wl,
    f32x4& a0, f32x4& a1, f32x4& a2) {
#pragma unroll
  for (int kk = 0; kk < 8; ++kk) {
    bf16x8 ah, al;
    split_a(hsrc + off + (kk << 5), ah, al);
    a0 = __builtin_amdgcn_mfma_f32_16x16x32_bf16(ah, wh[kk], a0, 0, 0, 0);
    a1 = __builtin_amdgcn_mfma_f32_16x16x32_bf16(ah, wl[kk], a1, 0, 0, 0);
    a2 = __builtin_amdgcn_mfma_f32_16x16x32_bf16(al, wh[kk], a2, 0, 0, 0);
  }
}

// poll-load one 8-elem fragment of epoch-tagged packed h; wave-uniform wait
static __device__ __forceinline__ void poll_frag(
    const unsigned long long* __restrict__ p, unsigned e, bf16x8& ah, bf16x8& al) {
  unsigned long long v[8];
  for (;;) {
    unsigned mn = 0xffffffffu;
#pragma unroll
    for (int j = 0; j < 8; ++j) {
      v[j] = __hip_atomic_load(p + j, __ATOMIC_RELAXED, __HIP_MEMORY_SCOPE_AGENT);
      unsigned t = (unsigned)(v[j] >> 32);
      mn = t < mn ? t : mn;
    }
    if (__all((int)(mn >= e))) break;
    __builtin_amdgcn_s_sleep(1);
  }
  u16x8 h8, l8;
#pragma unroll
  for (int j = 0; j < 8; ++j) {
    unsigned d = (unsigned)v[j];
    h8[j] = (unsigned short)(d >> 16);
    l8[j] = (unsigned short)d;
  }
  ah = __builtin_bit_cast(bf16x8, h8);
  al = __builtin_bit_cast(bf16x8, l8);
}

static __device__ __forceinline__ void dot3_poll(
    const unsigned long long* __restrict__ hsrc, int off, unsigned e,
    const bf16x8* wh, const bf16x8* wl,
    f32x4& a0, f32x4& a1, f32x4& a2) {
#pragma unroll
  for (int kk = 0; kk < 8; ++kk) {
    bf16x8 ah, al;
    poll_frag(hsrc + off + (kk << 5), e, ah, al);
    a0 = __builtin_amdgcn_mfma_f32_16x16x32_bf16(ah, wh[kk], a0, 0, 0, 0);
    a1 = __builtin_amdgcn_mfma_f32_16x16x32_bf16(ah, wl[kk], a1, 0, 0, 0);
    a2 = __builtin_amdgcn_mfma_f32_16x16x32_bf16(al, wh[kk], a2, 0, 0, 0);
  }
}

// ---------- r8 single-layer persistent LSTM (known-good fallback) ----------
__global__ __launch_bounds__(256) void lstm_persistent(
    const float* __restrict__ whT, const float* __restrict__ xw,
    const float* __restrict__ bh, const float* __restrict__ h0,
    const float* __restrict__ c0, float* __restrict__ ys,
    float* __restrict__ hfin, float* __restrict__ cfin,
    unsigned* __restrict__ flags, unsigned base) {
  __shared__ float red[4][16][16];
  const int tid  = threadIdx.x;
  const int lane = tid & 63;
  const int wave = tid >> 6;
  const int bid  = blockIdx.x;
  const int lc   = lane & 15;
  const int kg8  = (lane >> 4) << 3;
  const int wk   = wave << 8;

  const int gcol = (lc & 3) * 1024 + (bid << 2) + (lc >> 2);
  bf16x8 w_h[8], w_l[8];
  load_wset(whT, gcol, wk + kg8, w_h, w_l);

  const int ab = tid & 15;
  const int ai = tid >> 4;
  const int au = (bid << 2) + (ai & 3);
  float c_reg = 0.f, h_keep = 0.f;
  float bhv[4], xwv[4], xwn[4];
  if (tid < 64) {
    c_reg = c0[(ab << 10) + au];
#pragma unroll
    for (int g = 0; g < 4; ++g) bhv[g] = bh[(g << 10) + au];
#pragma unroll
    for (int g = 0; g < 4; ++g) xwv[g] = xw[(ab << 12) + (g << 10) + au];
  }
  const int hoff = (lc << 10) + wk + kg8;

  for (int s = 0; s < 256; ++s) {
    if (tid < 64 && s < 255) {
      const float* xn = xw + ((size_t)(s + 1) << 16);
#pragma unroll
      for (int g = 0; g < 4; ++g) xwn[g] = xn[(ab << 12) + (g << 10) + au];
    }
    const float* hsrc = (s == 0) ? h0 : (ys + ((size_t)(s - 1) << 14));
    f32x4 acc0 = {}, acc1 = {}, acc2 = {};
    dot3(hsrc, hoff, w_h, w_l, acc0, acc1, acc2);
    f32x4 a = acc0 + acc1 + acc2;
#pragma unroll
    for (int r = 0; r < 4; ++r) red[wave][(lane >> 4) * 4 + r][lc] = a[r];
    __syncthreads();
    if (tid < 64) {
      float pre[4];
#pragma unroll
      for (int g = 0; g < 4; ++g) {
        int c = (ai << 2) + g;
        pre[g] = red[0][ab][c] + red[1][ab][c] + red[2][ab][c] + red[3][ab][c]
               + xwv[g] + bhv[g];
      }
      float f  = 1.f / (1.f + expf(-pre[0]));
      float i_ = 1.f / (1.f + expf(-pre[1]));
      float o  = 1.f / (1.f + expf(-pre[2]));
      float g_ = tanhf(pre[3]);
      c_reg = f * c_reg + i_ * g_;
      float h = o * tanhf(c_reg);
      h_keep = h;
      __hip_atomic_store((unsigned*)ys + (((size_t)s << 14) + (ab << 10) + au),
                         __builtin_bit_cast(unsigned, h),
                         __ATOMIC_RELAXED, __HIP_MEMORY_SCOPE_AGENT);
#pragma unroll
      for (int g = 0; g < 4; ++g) xwv[g] = xwn[g];
    }
    if (wave == 0) {
      asm volatile("s_waitcnt vmcnt(0)" ::: "memory");
      if (lane == 0)
        __hip_atomic_store(&flags[bid], base + 1u + (unsigned)s, __ATOMIC_RELAXED, __HIP_MEMORY_SCOPE_AGENT);
      if (s < 255)
        poll_flags(flags, base + 1u + (unsigned)s, lane);
    }
    __syncthreads();
  }
  if (tid < 64) {
    hfin[(ab << 10) + au] = h_keep;
    cfin[(ab << 10) + au] = c_reg;
  }
}

// ---------- fused 2-layer LSTM: barrier-free epoch-tagged dataflow ----------
// h published as u64 {epoch<<32 | (bf16hi<<16|bf16lo)} via relaxed agent-scope
// atomic stores (tag travels WITH data -> no fences, no flags, no vmcnt).
// Consumers poll the data fragments directly (atomic u64 loads bypass stale
// L2; slots are step-unique). h1e[s] expects tag s+1; h2e[s] expects tag s+1.
__global__ __launch_bounds__(256) void lstm2_persistent(
    const float* __restrict__ wh1T, const float* __restrict__ wh2T,
    const unsigned short* __restrict__ wi2Th, const unsigned short* __restrict__ wi2Tl,
    const float* __restrict__ xw1, const float* __restrict__ bh,
    const float* __restrict__ bi, const float* __restrict__ hidden,
    unsigned long long* __restrict__ h1e, unsigned long long* __restrict__ h2e,
    float* __restrict__ ys2, float* __restrict__ nh) {
  __shared__ float red1[4][16][16];
  __shared__ float red2[4][16][16];
  const int tid  = threadIdx.x;
  const int lane = tid & 63;
  const int wave = tid >> 6;
  const int bid  = blockIdx.x;
  const int lc   = lane & 15;
  const int kg8  = (lane >> 4) << 3;
  const int wk   = wave << 8;
  const int wkoff = wk + kg8;

  const int gcol = (lc & 3) * 1024 + (bid << 2) + (lc >> 2);
  const size_t woff = ((size_t)gcol << 10) + wkoff;
  bf16x8 w1h[8], w1l[8], w2hh[8], w2hl[8];
  load_wset(wh1T, gcol, wkoff, w1h, w1l);
  load_wset(wh2T, gcol, wkoff, w2hh, w2hl);

  const float* h01 = hidden;
  const float* c01 = hidden + 16384;
  const float* h02 = hidden + 32768;
  const float* c02 = hidden + 49152;

  const int at = tid & 63;
  const int ab = at & 15;
  const int ai = at >> 4;
  const int au = (bid << 2) + ai;
  float c1 = 0.f, c2 = 0.f;
  float b1v[4], b2v[4], xwv[4], xwn[4];
  if (tid < 64) {
    c1 = c01[(ab << 10) + au];
#pragma unroll
    for (int g = 0; g < 4; ++g) b1v[g] = bh[(g << 10) + au];
#pragma unroll
    for (int g = 0; g < 4; ++g) xwv[g] = xw1[(ab << 12) + (g << 10) + au];
  } else if (tid < 128) {
    c2 = c02[(ab << 10) + au];
#pragma unroll
    for (int g = 0; g < 4; ++g)
      b2v[g] = bh[4096 + (g << 10) + au] + bi[4096 + (g << 10) + au];
  }

  const int hoff = (lc << 10) + wkoff;

  for (int k = 0; k <= 256; ++k) {
    const bool do1 = (k < 256);
    const bool do2 = (k >= 1);
    f32x4 a0 = {}, a1 = {}, a2 = {};
    f32x4 b0 = {}, b1 = {}, b2 = {};

    if (k == 0) {
      dot3(h01, hoff, w1h, w1l, a0, a1, a2);
    } else {
      // fused: poll h1e[k-1] (tag >= k) ONCE per fragment; feed layer-1 Wh1
      // (if k<256) and layer-2 Wi2 (always for k>=1).
      const unsigned long long* h1p = h1e + (((size_t)(k - 1)) << 14) + hoff;
#pragma unroll
      for (int kk = 0; kk < 8; ++kk) {
        bf16x8 ah, al;
        poll_frag(h1p + (kk << 5), (unsigned)k, ah, al);
        if (do1) {
          a0 = __builtin_amdgcn_mfma_f32_16x16x32_bf16(ah, w1h[kk], a0, 0, 0, 0);
          a1 = __builtin_amdgcn_mfma_f32_16x16x32_bf16(ah, w1l[kk], a1, 0, 0, 0);
          a2 = __builtin_amdgcn_mfma_f32_16x16x32_bf16(al, w1h[kk], a2, 0, 0, 0);
        }
        u16x8 wh8 = *(const u16x8*)(wi2Th + woff + (kk << 5));
        u16x8 wl8 = *(const u16x8*)(wi2Tl + woff + (kk << 5));
        b0 = __builtin_amdgcn_mfma_f32_16x16x32_bf16(ah, __builtin_bit_cast(bf16x8, wh8), b0, 0, 0, 0);
        b1 = __builtin_amdgcn_mfma_f32_16x16x32_bf16(ah, __builtin_bit_cast(bf16x8, wl8), b1, 0, 0, 0);
        b2 = __builtin_amdgcn_mfma_f32_16x16x32_bf16(al, __builtin_bit_cast(bf16x8, wh8), b2, 0, 0, 0);
      }
    }
    if (do2) {
      if (k == 1) dot3(h02, hoff, w2hh, w2hl, b0, b1, b2);
      else dot3_poll(h2e + (((size_t)(k - 2)) << 14), hoff, (unsigned)(k - 1),
                     w2hh, w2hl, b0, b1, b2);
    }

    if (do1) {
      f32x4 s = a0 + a1 + a2;
#pragma unroll
      for (int r = 0; r < 4; ++r) red1[wave][(lane >> 4) * 4 + r][lc] = s[r];
    }
    if (do2) {
      f32x4 s = b0 + b1 + b2;
#pragma unroll
      for (int r = 0; r < 4; ++r) red2[wave][(lane >> 4) * 4 + r][lc] = s[r];
    }
    __syncthreads();

    if (do1 && tid < 64) {
      float pre[4];
#pragma unroll
      for (int g = 0; g < 4; ++g) {
        int c = (ai << 2) + g;
        pre[g] = red1[0][ab][c] + red1[1][ab][c] + red1[2][ab][c] + red1[3][ab][c]
               + xwv[g] + b1v[g];
      }
      float f  = 1.f / (1.f + expf(-pre[0]));
      float i_ = 1.f / (1.f + expf(-pre[1]));
      float o  = 1.f / (1.f + expf(-pre[2]));
      float g_ = tanhf(pre[3]);
      c1 = f * c1 + i_ * g_;
      float h = o * tanhf(c1);
      unsigned short hh, ll; split1(h, hh, ll);
      unsigned long long pk = ((unsigned long long)(unsigned)(k + 1) << 32)
                            | (unsigned long long)(((unsigned)hh << 16) | (unsigned)ll);
      __hip_atomic_store(&h1e[((size_t)k << 14) + (ab << 10) + au], pk,
                         __ATOMIC_RELAXED, __HIP_MEMORY_SCOPE_AGENT);
      if (k == 255) {
        nh[(ab << 10) + au] = h;
        nh[16384 + (ab << 10) + au] = c1;
      }
      // prefetch next xw (plain cached; overlaps next iteration's polling)
      if (k < 255) {
        const float* xn = xw1 + ((size_t)(k + 1) << 16);
#pragma unroll
        for (int g = 0; g < 4; ++g) xwn[g] = xn[(ab << 12) + (g << 10) + au];
#pragma unroll
        for (int g = 0; g < 4; ++g) xwv[g] = xwn[g];
      }
    }
    if (do2 && wave == 1) {
      int s2 = k - 1;
      float pre[4];
#pragma unroll
      for (int g = 0; g < 4; ++g) {
        int c = (ai << 2) + g;
        pre[g] = red2[0][ab][c] + red2[1][ab][c] + red2[2][ab][c] + red2[3][ab][c]
               + b2v[g];
      }
      float f  = 1.f / (1.f + expf(-pre[0]));
      float i_ = 1.f / (1.f + expf(-pre[1]));
      float o  = 1.f / (1.f + expf(-pre[2]));
      float g_ = tanhf(pre[3]);
      c2 = f * c2 + i_ * g_;
      float h = o * tanhf(c2);
      ys2[((size_t)s2 << 14) + (ab << 10) + au] = h;   // plain store (read after kernel)
      unsigned short hh, ll; split1(h, hh, ll);
      unsigned long long pk = ((unsigned long long)(unsigned)(s2 + 1) << 32)
                            | (unsigned long long)(((unsigned)hh << 16) | (unsigned)ll);
      __hip_atomic_store(&h2e[((size_t)s2 << 14) + (ab << 10) + au], pk,
                         __ATOMIC_RELAXED, __HIP_MEMORY_SCOPE_AGENT);
      if (s2 == 255) {
        nh[32768 + (ab << 10) + au] = h;
        nh[49152 + (ab << 10) + au] = c2;
      }
    }
    __syncthreads();   // protect red1/red2 for next iteration
  }
}

// ---------- prep kernels ----------
__global__ __launch_bounds__(256) void embed_gather_split(
    const int* __restrict__ tokens, const float* __restrict__ emb,
    unsigned short* __restrict__ xh, unsigned short* __restrict__ xl) {
  int sb = blockIdx.x;
  int tok = tokens[sb];
  f32x4 v = ((const f32x4*)(emb + (size_t)tok * 1024))[threadIdx.x];
  u16x4 h, l;
#pragma unroll
  for (int j = 0; j < 4; ++j) { unsigned short hh, ll; split1(v[j], hh, ll); h[j] = hh; l[j] = ll; }
  size_t o = (size_t)sb * 1024 + threadIdx.x * 4;
  *(u16x4*)(xh + o) = h;
  *(u16x4*)(xl + o) = l;
}

__global__ __launch_bounds__(256) void split_mat(
    const float* __restrict__ x, unsigned short* __restrict__ xh,
    unsigned short* __restrict__ xl) {
  size_t i = (size_t)blockIdx.x * 256 + threadIdx.x;
  f32x4 v = ((const f32x4*)x)[i];
  u16x4 h, l;
#pragma unroll
  for (int j = 0; j < 4; ++j) { unsigned short hh, ll; split1(v[j], hh, ll); h[j] = hh; l[j] = ll; }
  *(u16x4*)(xh + i * 4) = h;
  *(u16x4*)(xl + i * 4) = l;
}

__global__ void split_transpose_w(
    const float* __restrict__ W, unsigned short* __restrict__ WTh,
    unsigned short* __restrict__ WTl, int K, int N) {
  __shared__ float tile[32][33];
  int n0 = blockIdx.x << 5;
  int k0 = blockIdx.y << 5;
  int tx = threadIdx.x, ty = threadIdx.y;  // 32 x 8
#pragma unroll
  for (int i = 0; i < 32; i += 8) {
    int n = n0 + tx;
    tile[ty + i][tx] = (n < N) ? W[(size_t)(k0 + ty + i) * N + n] : 0.f;
  }
  __syncthreads();
#pragma unroll
  for (int i = 0; i < 32; i += 8) {
    int n = n0 + ty + i;
    float v = tile[tx][ty + i];
    unsigned short h, l; split1(v, h, l);
    WTh[(size_t)n * K + k0 + tx] = h;
    WTl[(size_t)n * K + k0 + tx] = l;
  }
}

// [1024][4096] f32 -> [4096][1024] f32
__global__ void transpose1(const float* __restrict__ src, float* __restrict__ dst) {
  __shared__ float tile[32][33];
  int c0 = blockIdx.x << 5;
  int k0 = blockIdx.y << 5;
  int tx = threadIdx.x, ty = threadIdx.y;  // 32 x 8
#pragma unroll
  for (int i = 0; i < 32; i += 8)
    tile[ty + i][tx] = src[(size_t)(k0 + ty + i) * 4096 + c0 + tx];
  __syncthreads();
#pragma unroll
  for (int i = 0; i < 32; i += 8)
    dst[(size_t)(c0 + ty + i) * 1024 + k0 + tx] = tile[tx][ty + i];
}

// ---------- host ----------
extern "C" void kernel_launch(void* const* d_in, const int* in_sizes, int n_in,
                              void* d_out, int out_size, void* d_ws, size_t ws_size,
                              hipStream_t stream) {
  (void)in_sizes; (void)n_in; (void)out_size; (void)ws_size;
  const int*   tokens    = (const int*)  d_in[0];
  const float* hidden    = (const float*)d_in[1];
  const float* embedding = (const float*)d_in[2];
  const float* wi        = (const float*)d_in[3];
  const float* bi        = (const float*)d_in[4];
  const float* wh        = (const float*)d_in[5];
  const float* bh        = (const float*)d_in[6];
  const float* wdec      = (const float*)d_in[7];
  const float* bdec      = (const float*)d_in[8];

  float* out     = (float*)d_out;
  float* out_res = out;                                   // 256*16*50257
  float* out_nh  = out + (size_t)205852672;               // 2*2*16*1024
  float* out_x   = out + (size_t)205852672 + 65536;       // 256*16*1024
  // epoch-tagged packed-h scratch in out_res (decode overwrites at the end)
  unsigned long long* h1e = (unsigned long long*)out_res;            // 4194304 u64
  unsigned long long* h2e = h1e + 4194304;                           // 4194304 u64
  float* ys0_fb  = out_res + 16777216;                    // fallback h1 seq (f32)

  // ---- workspace layout ----
  float* ws    = (float*)d_ws;
  float* whT   = ws;                        // 2*4194304 f (layers contiguous)
  float* xwb   = whT + 8388608;             // 16777216 f
  unsigned* flags = (unsigned*)(xwb + 16777216);  // 16384 u32 (fallback only)
  unsigned short* u16base = (unsigned short*)(flags + 16384);
  unsigned short* Ah_s  = u16base;                 // 4194304
  unsigned short* Al_s  = Ah_s + 4194304;          // 4194304
  unsigned short* wiTh  = Al_s + 4194304;          // 4194304 (layer 0)
  unsigned short* wiTl  = wiTh + 4194304;          // 4194304
  unsigned short* wi2Th = wiTl + 4194304;          // 4194304 (layer 1)
  unsigned short* wi2Tl = wi2Th + 4194304;         // 4194304
  unsigned short* wdTh  = wi2Tl + 4194304;         // 51511296
  unsigned short* wdTl  = wdTh + 51511296;         // 51511296

  // zero epoch tags (scratch is poisoned / holds stale decode output between
  // replays; epoch field must start < 1)
  hipMemsetAsync(h1e, 0, (size_t)8388608 * 8, stream);
  hipMemsetAsync(flags, 0, 16384 * sizeof(unsigned), stream);
  transpose1<<<dim3(128, 32), dim3(32, 8), 0, stream>>>(wh, whT);
  transpose1<<<dim3(128, 32), dim3(32, 8), 0, stream>>>(wh + 4194304, whT + 4194304);
  embed_gather_split<<<4096, 256, 0, stream>>>(tokens, embedding, Ah_s, Al_s);
  split_transpose_w<<<dim3(128, 32), dim3(32, 8), 0, stream>>>(wi, wiTh, wiTl, 1024, 4096);
  split_transpose_w<<<dim3(128, 32), dim3(32, 8), 0, stream>>>(wi + 4194304, wi2Th, wi2Tl, 1024, 4096);
  split_transpose_w<<<dim3(1572, 32), dim3(32, 8), 0, stream>>>(wdec, wdTh, wdTl, 1024, 50257);

  // xw1 = emb @ wi0^T + bi0 (both paths need this)
  gemm_ps<<<dim3(32, 32), 256, 0, stream>>>(
      Ah_s, Al_s, wiTh, wiTl, bi, xwb, 4096, 4096, 1024);

  // ---- fused dataflow path, gated on occupancy + launch acceptance ----
  bool fused_ok = false;
  int nb = 0;
  hipError_t qerr = hipOccupancyMaxActiveBlocksPerMultiprocessor(
      &nb, (const void*)lstm2_persistent, 256, 0);
  if (qerr == hipSuccess && nb >= 1) {
    const float* p_wh1T = whT; const float* p_wh2T = whT + 4194304;
    const unsigned short* p_wi2Th = wi2Th; const unsigned short* p_wi2Tl = wi2Tl;
    const float* p_xw1 = xwb;  const float* p_bh = bh;   const float* p_bi = bi;
    const float* p_hid = hidden;
    unsigned long long* p_h1 = h1e; unsigned long long* p_h2 = h2e;
    float* p_ys2 = out_x; float* p_nh = out_nh;
    void* args[] = { &p_wh1T, &p_wh2T, &p_wi2Th, &p_wi2Tl, &p_xw1, &p_bh, &p_bi,
                     &p_hid, &p_h1, &p_h2, &p_ys2, &p_nh };
    hipError_t cerr = hipLaunchCooperativeKernel((const void*)lstm2_persistent,
                                                 dim3(256), dim3(256), args, 0, stream);
    fused_ok = (cerr == hipSuccess);
  }

  if (!fused_ok) {
    // ---- exact r8 fallback: per-layer coop kernels (dense flags) ----
    unsigned* fl2 = flags + 8192;
    for (int l = 0; l < 2; ++l) {
      if (l == 1) {
        gemm_ps<<<dim3(32, 32), 256, 0, stream>>>(
            Ah_s, Al_s, wi2Th, wi2Tl, bi + 4096, xwb, 4096, 4096, 1024);
      }
      const float* wT  = whT + (size_t)l * 4194304;
      const float* xwp = xwb;
      const float* bhl = bh + l * 4096;
      const float* h0p = hidden + (size_t)l * 32768;
      const float* c0p = h0p + 16384;
      float* ysp  = (l == 0) ? ys0_fb : out_x;
      float* hfin = out_nh + (size_t)l * 32768;
      float* cfin = hfin + 16384;
      unsigned basev = (unsigned)(l * 256);
      void* args[] = { &wT, &xwp, &bhl, &h0p, &c0p, &ysp, &hfin, &cfin, &fl2, &basev };
      hipLaunchCooperativeKernel((const void*)lstm_persistent,
                                 dim3(256), dim3(256), args, 0, stream);
      split_mat<<<4096, 256, 0, stream>>>(ysp, Ah_s, Al_s);
    }
  } else {
    split_mat<<<4096, 256, 0, stream>>>(out_x, Ah_s, Al_s);
  }

  // decode
  gemm_ps<<<dim3(32, 393), 256, 0, stream>>>(
      Ah_s, Al_s, wdTh, wdTl, bdec, out_res, 4096, 50257, 1024);
}